// Round 3
// baseline (2419.894 us; speedup 1.0000x reference)
//
#include <hip/hip_runtime.h>
#include <hip/hip_bf16.h>

// Problem dims
static const int kB = 128, kN = 49, kC = 2048, kD = 512, kE = 512, kV = 10000, kT = 20;

typedef __bf16 bf16x8 __attribute__((ext_vector_type(8)));
typedef float  f32x4v __attribute__((ext_vector_type(4)));
typedef _Float16 h8_t __attribute__((ext_vector_type(8)));
typedef _Float16 h2v_t __attribute__((ext_vector_type(2)));
typedef unsigned short u16;
typedef unsigned int u32;

#if defined(__has_builtin)
#if __has_builtin(__builtin_amdgcn_fdot2)
#define HAS_FDOT2 1
#endif
#endif
#ifndef HAS_FDOT2
#define HAS_FDOT2 0
#endif

#define AS1 __attribute__((address_space(1)))
#define AS3 __attribute__((address_space(3)))

__device__ __forceinline__ float sigmoidf_(float x){ return 1.f/(1.f+expf(-x)); }
__device__ __forceinline__ u16 f2b(float x){ __hip_bfloat16 h = __float2bfloat16(x); return *(u16*)&h; }
__device__ __forceinline__ float bu2f(u32 u){ u32 w = u << 16; union{u32 u; float f;} c; c.u = w; return c.f; }

// ================= bf16 MFMA NT GEMM =================
// C[M,N] = act(A[M,K]@W[N,K]^T + bias + add1[m&a1mask]), fp32 acc.
// REQUIRES: M % 128 == 0; W has >= ceil(N/128)*128 readable rows (padded
// workspace); staging uses global_load_lds width-16 (no bounds checks).
#define TBM 128
#define TBN 128
#define TBK 32

__global__ __launch_bounds__(256) void gemm_bf16(
    const u16* __restrict__ A, int lda,
    const u16* __restrict__ W, int ldw,
    float* __restrict__ C, u16* __restrict__ Cbf, int ldc,
    int M, int N, int K,
    const float* __restrict__ bias,
    const float* __restrict__ add1, int ld1, int a1mask,
    int act)
{
    __shared__ __align__(16) u16 As[TBM*TBK];
    __shared__ __align__(16) u16 Bs[TBN*TBK];
    const int tid = threadIdx.x;
    const int bm = blockIdx.y * TBM;
    const int bn = blockIdx.x * TBN;
    const int wave = tid >> 6, lane = tid & 63;
    const int wm = (wave >> 1) * 64, wn = (wave & 1) * 64;
    const int lm = lane & 15, quad = lane >> 4;
    f32x4v acc[4][4] = {};
    for (int k0 = 0; k0 < K; k0 += TBK) {
        #pragma unroll
        for (int h = 0; h < 2; ++h) {
            const int slot = h*256 + tid;           // 0..511
            const int row = slot >> 2, kf = (slot & 3)*8;
            const int wbase = (h*256 + (tid & 448))*8;  // wave-uniform, u16 units
            __builtin_amdgcn_global_load_lds((const AS1 u32*)(A + (size_t)(bm + row)*lda + k0 + kf),
                                             (AS3 u32*)(As + wbase), 16, 0, 0);
            __builtin_amdgcn_global_load_lds((const AS1 u32*)(W + (size_t)(bn + row)*ldw + k0 + kf),
                                             (AS3 u32*)(Bs + wbase), 16, 0, 0);
        }
        __syncthreads();
        bf16x8 afr[4], bfr[4];
        #pragma unroll
        for (int i = 0; i < 4; ++i) afr[i] = *(const bf16x8*)&As[(wm + i*16 + lm)*TBK + quad*8];
        #pragma unroll
        for (int j = 0; j < 4; ++j) bfr[j] = *(const bf16x8*)&Bs[(wn + j*16 + lm)*TBK + quad*8];
        #pragma unroll
        for (int i = 0; i < 4; ++i)
            #pragma unroll
            for (int j = 0; j < 4; ++j)
                acc[i][j] = __builtin_amdgcn_mfma_f32_16x16x32_bf16(afr[i], bfr[j], acc[i][j], 0, 0, 0);
        __syncthreads();
    }
    #pragma unroll
    for (int i = 0; i < 4; ++i) {
        int mbase = bm + wm + i*16 + quad*4;
        #pragma unroll
        for (int j = 0; j < 4; ++j) {
            int n = bn + wn + j*16 + lm;
            if (n >= N) continue;
            float bv = bias ? bias[n] : 0.f;
            #pragma unroll
            for (int rr2 = 0; rr2 < 4; ++rr2) {
                int m = mbase + rr2;
                float v = acc[i][j][rr2] + bv;
                if (add1) v += add1[(size_t)(m & a1mask)*ld1 + n];
                if (act == 1) v = fmaxf(v, 0.f);
                else if (act == 2) v = tanhf(v);
                if (C)   C[(size_t)m*ldc + n] = v;
                if (Cbf) Cbf[(size_t)m*ldc + n] = f2b(v);
            }
        }
    }
}

// ================= fused conversion kernels =================
// img fp32 [B][49][2048] -> bf16 (same layout) AND mean over n -> bf16 [B][2048]
__global__ __launch_bounds__(256) void img_cvt_mean_k(const float* __restrict__ img,
                                                      u16* __restrict__ img_bf,
                                                      u16* __restrict__ meanb){
    int idx = blockIdx.x*256 + threadIdx.x;       // B * C/8 = 32768
    int b = idx >> 8, c8 = idx & 255;
    const float* p = img + (size_t)b*kN*kC + c8*8;
    f32x4v s0 = {0,0,0,0}, s1 = {0,0,0,0};
    for (int n = 0; n < kN; ++n){
        f32x4v f0 = *(const f32x4v*)(p + (size_t)n*kC);
        f32x4v f1 = *(const f32x4v*)(p + (size_t)n*kC + 4);
        s0 += f0; s1 += f1;
        union { u16 u[8]; uint4 v; } pk;
        pk.u[0]=f2b(f0[0]); pk.u[1]=f2b(f0[1]); pk.u[2]=f2b(f0[2]); pk.u[3]=f2b(f0[3]);
        pk.u[4]=f2b(f1[0]); pk.u[5]=f2b(f1[1]); pk.u[6]=f2b(f1[2]); pk.u[7]=f2b(f1[3]);
        *(uint4*)(img_bf + ((size_t)(b*kN + n))*kC + c8*8) = pk.v;
    }
    const float inv = 1.f/(float)kN;
    union { u16 u[8]; uint4 v; } pm;
    pm.u[0]=f2b(s0[0]*inv); pm.u[1]=f2b(s0[1]*inv); pm.u[2]=f2b(s0[2]*inv); pm.u[3]=f2b(s0[3]*inv);
    pm.u[4]=f2b(s1[0]*inv); pm.u[5]=f2b(s1[1]*inv); pm.u[6]=f2b(s1[2]*inv); pm.u[7]=f2b(s1[3]*inv);
    *(uint4*)(meanb + (size_t)b*kC + c8*8) = pm.v;
}

// all weight conversions in ONE kernel via descriptor table.
// mode 0: fp32[rows][src_ld] (first Kc8*8 cols) -> bf16 [rows][Kc8*8]
// mode 1: fp32[rows][src_ld] (K=512) -> f16 interleaved [64][Ntot][8] at row n_off
struct CvtDesc {
    const float* src;
    unsigned long long dst;
    int src_ld, Kshift, mode, n_off, Ntot, start;
};
struct CvtTab { CvtDesc d[17]; int total; };

__global__ __launch_bounds__(256) void multi_cvt_k(CvtTab tab){
    for (int idx = blockIdx.x*256 + threadIdx.x; idx < tab.total; idx += gridDim.x*256){
        int di = 0;
        #pragma unroll
        for (int i = 1; i < 17; ++i) if (idx >= tab.d[i].start) di = i;
        const CvtDesc D = tab.d[di];
        int rel = idx - D.start;
        int rr = rel >> D.Kshift, kc = rel - (rr << D.Kshift);
        const float* p = D.src + (size_t)rr*D.src_ld + kc*8;
        f32x4v f0 = *(const f32x4v*)p, f1 = *(const f32x4v*)(p+4);
        if (D.mode == 0){
            union { u16 u[8]; uint4 v; } pk;
            pk.u[0]=f2b(f0[0]); pk.u[1]=f2b(f0[1]); pk.u[2]=f2b(f0[2]); pk.u[3]=f2b(f0[3]);
            pk.u[4]=f2b(f1[0]); pk.u[5]=f2b(f1[1]); pk.u[6]=f2b(f1[2]); pk.u[7]=f2b(f1[3]);
            *(uint4*)((u16*)D.dst + (((size_t)rr << D.Kshift) + kc)*8) = pk.v;
        } else {
            h8_t o;
            o[0]=(_Float16)f0[0]; o[1]=(_Float16)f0[1]; o[2]=(_Float16)f0[2]; o[3]=(_Float16)f0[3];
            o[4]=(_Float16)f1[0]; o[5]=(_Float16)f1[1]; o[6]=(_Float16)f1[2]; o[7]=(_Float16)f1[3];
            *(h8_t*)((_Float16*)D.dst + ((size_t)kc*D.Ntot + D.n_off + rr)*8) = o;
        }
    }
}

// bias2560 = [bih+bhh (2048); 0 (512)]; bcat3 = [bb|bhi|bmi]; zero barrier ctrs
__global__ __launch_bounds__(256) void bias_prep_k(const float* bih, const float* bhh,
                                                   const float* bb, const float* bhi, const float* bmi,
                                                   float* bias2560, float* bcat3, int* bctr){
    int i = blockIdx.x*256 + threadIdx.x;
    if (i < kT) bctr[i] = 0;
    if (i < 2048) bias2560[i] = bih[i] + bhh[i];
    else if (i < 2560) bias2560[i] = 0.f;
    else if (i < 4096){
        int j = i - 2560;
        bcat3[j] = (j < 512) ? bb[j] : (j < 1024 ? bhi[j-512] : bmi[j-1024]);
    }
}

// we[t*B+b][e] bf16
__global__ __launch_bounds__(256) void emb_gather_k(const int* __restrict__ target,
                                                    const float* __restrict__ emb,
                                                    u16* __restrict__ we){
    int idx = blockIdx.x*256 + threadIdx.x;       // T*B*E
    int e = idx & (kE-1);
    int rr = idx >> 9;                            // t*B + b
    int b = rr & 127, t = rr >> 7;
    float v = 0.f;
    if (t > 0){ int tok = target[b*kT + (t-1)]; v = emb[(size_t)tok*kE + e]; }
    we[idx] = f2b(v);
}

// ================= LSTM recurrence: 256 blocks (2 per batch), grid barrier/t =================
__device__ __forceinline__ float dot8f(h8_t a, h8_t b, float c){
#if HAS_FDOT2
    const h2v_t* ap = (const h2v_t*)&a;
    const h2v_t* bp = (const h2v_t*)&b;
    c = __builtin_amdgcn_fdot2(ap[0], bp[0], c, false);
    c = __builtin_amdgcn_fdot2(ap[1], bp[1], c, false);
    c = __builtin_amdgcn_fdot2(ap[2], bp[2], c, false);
    c = __builtin_amdgcn_fdot2(ap[3], bp[3], c, false);
#else
    #pragma unroll
    for (int i = 0; i < 8; ++i) c = fmaf((float)a[i], (float)b[i], c);
#endif
    return c;
}

__global__ __launch_bounds__(512) void scan_k(
    const float* __restrict__ initC,       // [128][1536] vg|h0|m0 (fp32)
    const float* __restrict__ xall,        // [20][128][2560]
    const _Float16* __restrict__ Wrec,     // il [64][2560][8]
    _Float16* __restrict__ hbuf,           // [2][128][512] f16 (cross-block h exchange)
    int* __restrict__ bctr,                // [kT] zeroed by bias_prep_k
    u16* __restrict__ h2_bf,               // [20*128][512] bf16 (row t*128+b)
    u16* __restrict__ gtv_bf)              // [20*128][512] bf16
{
    const int blk = blockIdx.x;            // 0..255
    const int b = blk >> 1, p = blk & 1;   // p: which 256-output half
    const int tid = threadIdx.x;
    const int out_l = tid & 255;
    const int out = p*256 + out_l;         // global out in [0,512)
    const int kh = tid >> 8;               // K-half 0/1
    __shared__ __align__(16) _Float16 sh[512];
    __shared__ float spart[256][5];

    float m_reg = (kh == 0) ? initC[(size_t)b*1536 + 1024 + out] : 0.f;

    for (int t = 0; t < kT; ++t){
        // load full h into LDS
        if (t == 0){
            if (tid < 512) sh[tid] = (_Float16)initC[(size_t)b*1536 + 512 + tid];
        } else {
            if (tid < 64) *(h8_t*)&sh[tid*8] = *(const h8_t*)&hbuf[((size_t)(t&1))*128*512 + (size_t)b*512 + tid*8];
        }
        __syncthreads();
        // half-GEMV: this block's 256 outputs (5 gate groups), kh splits K
        float acc[5] = {0.f, 0.f, 0.f, 0.f, 0.f};
        const int kc0 = kh*32;
        #pragma unroll 2
        for (int kc = kc0; kc < kc0 + 32; ++kc){
            h8_t hv = *(const h8_t*)&sh[kc*8];
            const _Float16* wb = Wrec + (size_t)kc*2560*8;
            #pragma unroll
            for (int j = 0; j < 5; ++j){
                h8_t wv = *(const h8_t*)&wb[(size_t)(out + 512*j)*8];
                acc[j] = dot8f(hv, wv, acc[j]);
            }
        }
        if (kh == 1){
            #pragma unroll
            for (int j = 0; j < 5; ++j) spart[out_l][j] = acc[j];
        }
        __syncthreads();
        if (kh == 0){
            const float* xrow = xall + ((size_t)t*kB + b)*2560;
            #pragma unroll
            for (int j = 0; j < 5; ++j) acc[j] += spart[out_l][j] + xrow[out + 512*j];
            float i_g = sigmoidf_(acc[0]);
            float f_g = sigmoidf_(acc[1]);
            float g_g = tanhf(acc[2]);
            float o_g = sigmoidf_(acc[3]);
            m_reg = f_g*m_reg + i_g*g_g;
            float tm = tanhf(m_reg);
            float h2v = o_g*tm;
            float gtvv = sigmoidf_(acc[4])*tm;
            size_t row = (size_t)t*kB + b;
            h2_bf[row*512 + out] = f2b(h2v);
            gtv_bf[row*512 + out] = f2b(gtvv);
            hbuf[((size_t)((t+1)&1))*128*512 + (size_t)b*512 + out] = (_Float16)h2v;
        }
        if (t < kT-1){
            // grid barrier: release writes, arrive, spin, acquire
            __threadfence();
            __syncthreads();
            if (tid == 0){
                atomicAdd(&bctr[t], 1);
                while (__hip_atomic_load(&bctr[t], __ATOMIC_RELAXED, __HIP_MEMORY_SCOPE_AGENT) < 256)
                    __builtin_amdgcn_s_sleep(2);
            }
            __syncthreads();
            __threadfence();
        }
    }
}

// ================= batched attention kernel: one block per (t,b) row =================
__global__ __launch_bounds__(256) void attn_k(
    const float* __restrict__ gH_all,      // [2560][49]
    const float* __restrict__ sWs_all,     // [2560][49]
    const float* __restrict__ H_all,       // [2560][512] fp32
    const float* __restrict__ s_all,       // [2560][512] fp32
    const u16* __restrict__ Vf_bf,         // [128*49][512] bf16
    const float* __restrict__ zbase,       // [128][49][49]
    const float* __restrict__ wh,          // [49]
    u16* __restrict__ Hc_bf,               // [2560][512] bf16
    float* __restrict__ attn_out)          // [128][20][49] fp32
{
    const int r = blockIdx.x, tid = threadIdx.x;   // r = t*128 + b
    const int b = r & 127, t = r >> 7;
    __shared__ float sgH[52], ssWs[52], swh[52], sz[52], salpha[52];

    if (tid < 49){
        sgH[tid]  = gH_all [(size_t)r*49 + tid];
        ssWs[tid] = sWs_all[(size_t)r*49 + tid];
        swh[tid]  = wh[tid];
    }
    __syncthreads();
    if (tid < 49){
        const float* zb = zbase + (size_t)b*2401 + (size_t)tid*49;
        float a = 0.f;
        #pragma unroll
        for (int k = 0; k < 49; ++k) a += tanhf(zb[k] + sgH[k]) * swh[k];
        sz[tid] = a;
    }
    if (tid == 64){
        float a = 0.f;
        #pragma unroll
        for (int k = 0; k < 49; ++k) a += tanhf(ssWs[k] + sgH[k]) * swh[k];
        sz[49] = a;
    }
    __syncthreads();
    if (tid < 64){
        float val = (tid < 50) ? sz[tid] : -1e30f;
        float mx = val;
        #pragma unroll
        for (int o = 32; o > 0; o >>= 1) mx = fmaxf(mx, __shfl_xor(mx, o));
        float e = (tid < 50) ? __expf(val - mx) : 0.f;
        float ssum = e;
        #pragma unroll
        for (int o = 32; o > 0; o >>= 1) ssum += __shfl_xor(ssum, o);
        float a = e/ssum;
        if (tid < 50) salpha[tid] = a;
        if (tid < 49) attn_out[((size_t)b*kT + t)*kN + tid] = a;
    }
    __syncthreads();
    for (int d = tid; d < 512; d += 256){
        float a = salpha[49] * s_all[(size_t)r*512 + d];
        const u16* vf = Vf_bf + (size_t)b*49*512 + d;
        #pragma unroll
        for (int n = 0; n < 49; ++n) a = fmaf(salpha[n], bu2f(vf[(size_t)n*512]), a);
        Hc_bf[(size_t)r*512 + d] = f2b(H_all[(size_t)r*512 + d] + a);
    }
}

// ================= log-softmax: read bf16 logits row (t*128+b), write fp32 row (b*20+t) =================
__global__ __launch_bounds__(256) void logsoftmax_k(const u16* __restrict__ logits_bf,
                                                    float* __restrict__ out0)
{
    const int r = blockIdx.x, tid = threadIdx.x;   // r = b*20+t
    const int b = r / 20, t = r - b*20;
    const u16* L = logits_bf + (size_t)(t*kB + b)*kV;
    __shared__ float rm[256], rs[256];
    float m = -1e30f, s = 0.f;
    for (int c = tid; c < kV/8; c += 256){
        uint4 v = *(const uint4*)(L + c*8);
        u32 w[4] = {v.x, v.y, v.z, v.w};
        #pragma unroll
        for (int j = 0; j < 4; ++j){
            float x0 = bu2f(w[j] & 0xffff), x1 = bu2f(w[j] >> 16);
            float nm = fmaxf(m, fmaxf(x0, x1));
            s = s*__expf(m - nm) + __expf(x0 - nm) + __expf(x1 - nm);
            m = nm;
        }
    }
    rm[tid] = m; rs[tid] = s; __syncthreads();
    for (int st = 128; st > 0; st >>= 1){
        if (tid < st){
            float m2 = rm[tid + st], s2 = rs[tid + st];
            float nm = fmaxf(rm[tid], m2);
            rs[tid] = rs[tid]*__expf(rm[tid] - nm) + s2*__expf(m2 - nm);
            rm[tid] = nm;
        }
        __syncthreads();
    }
    float lse = rm[0] + logf(rs[0]);
    float* D = out0 + (size_t)r*kV;
    for (int c = tid; c < kV/8; c += 256){
        uint4 v = *(const uint4*)(L + c*8);
        u32 w[4] = {v.x, v.y, v.z, v.w};
        f32x4v o0, o1;
        o0[0]=bu2f(w[0]&0xffff)-lse; o0[1]=bu2f(w[0]>>16)-lse;
        o0[2]=bu2f(w[1]&0xffff)-lse; o0[3]=bu2f(w[1]>>16)-lse;
        o1[0]=bu2f(w[2]&0xffff)-lse; o1[1]=bu2f(w[2]>>16)-lse;
        o1[2]=bu2f(w[3]&0xffff)-lse; o1[3]=bu2f(w[3]>>16)-lse;
        *(f32x4v*)(D + c*8) = o0;
        *(f32x4v*)(D + c*8 + 4) = o1;
    }
}

extern "C" void kernel_launch(void* const* d_in, const int* in_sizes, int n_in,
                              void* d_out, int out_size, void* d_ws, size_t ws_size,
                              hipStream_t stream)
{
    const float* img   = (const float*)d_in[0];
    const int*   target= (const int*)  d_in[1];
    const float* emb   = (const float*)d_in[2];
    const float* Wa    = (const float*)d_in[3];
    const float* ba    = (const float*)d_in[4];
    const float* Wb    = (const float*)d_in[5];
    const float* bb    = (const float*)d_in[6];
    const float* Whi   = (const float*)d_in[7];
    const float* bhi   = (const float*)d_in[8];
    const float* Wmi   = (const float*)d_in[9];
    const float* bmi   = (const float*)d_in[10];
    const float* Wih   = (const float*)d_in[11];
    const float* bih   = (const float*)d_in[12];
    const float* Whh   = (const float*)d_in[13];
    const float* bhh   = (const float*)d_in[14];
    const float* Wv    = (const float*)d_in[15];
    const float* Wg    = (const float*)d_in[16];
    const float* wh    = (const float*)d_in[17];
    const float* W_H   = (const float*)d_in[18];
    const float* Wx    = (const float*)d_in[19];
    const float* Wh2   = (const float*)d_in[20];
    const float* Wsm   = (const float*)d_in[21];
    const float* Wc    = (const float*)d_in[22];
    const float* bc    = (const float*)d_in[23];
    const float* Wfc   = (const float*)d_in[24];
    const float* bfc   = (const float*)d_in[25];
    const float* Wp    = (const float*)d_in[26];
    const float* bp    = (const float*)d_in[27];
    (void)in_sizes; (void)n_in; (void)out_size; (void)ws_size;

    float* out0 = (float*)d_out;                       // [B*T, V] logprobs (row b*20+t)
    float* attn_out = out0 + (size_t)kB*kT*kV;         // [B, T, N]

    char* base = (char*)d_ws;
    size_t off = 0;
    auto alloc = [&](size_t bytes)->char*{
        char* p = base + off;
        off += ((bytes + 255) & ~(size_t)255);
        return p;
    };
    // fixed region (W arrays padded to 128-row multiples for unchecked staging)
    u16* Wa_bf     = (u16*)alloc((size_t)kD*kC*2);
    u16* Winit_bf  = (u16*)alloc((size_t)1536*kC*2);
    u16* Wv_bf     = (u16*)alloc((size_t)128*kD*2);           // 49 -> 128 rows
    u16* Wp_bf     = (u16*)alloc((size_t)10112*kD*2);         // 10000 -> 10112 rows
    u16* Wfirst_bf = (u16*)alloc((size_t)2560*512*2); // [Wih[:, :512]; Wx[:, :512]]
    u16* Wlast_bf  = (u16*)alloc((size_t)2560*512*2); // [Wih[:, 512:]; Wx[:, 512:]]
    _Float16* Wrec_il = (_Float16*)alloc((size_t)2560*512*2);
    u16* WH_bf     = (u16*)alloc((size_t)512*512*2);
    u16* Wc_bf     = (u16*)alloc((size_t)512*512*2);
    u16* Wg_bf     = (u16*)alloc((size_t)128*512*2);          // 49 -> 128 rows
    u16* Ws_bf     = (u16*)alloc((size_t)128*512*2);          // 49 -> 128 rows
    u16* Wfc_bf    = (u16*)alloc((size_t)512*512*2);
    float* bias2560 = (float*)alloc(2560*4);
    float* bcat3    = (float*)alloc(1536*4);
    u16* meanb_bf   = (u16*)alloc((size_t)kB*kC*2);
    float* initC    = (float*)alloc((size_t)kB*1536*4);
    u16* init_bf    = (u16*)alloc((size_t)kB*1536*2);
    u16* Vf_bf      = (u16*)alloc((size_t)kB*kN*kD*2);
    float* zbase    = (float*)alloc((size_t)kB*kN*kN*4);
    u16* we_bf      = (u16*)alloc((size_t)kT*kB*kE*2);
    float* gbase    = (float*)alloc((size_t)kB*2560*4);
    u16* outbf      = (u16*)alloc((size_t)kT*kB*kD*2);
    u16* h2_bf      = (u16*)alloc((size_t)kT*kB*kD*2);
    u16* gtv_bf     = (u16*)alloc((size_t)kT*kB*kD*2);
    _Float16* hbuf  = (_Float16*)alloc((size_t)2*kB*kD*2);
    int* bctr       = (int*)alloc(kT*4);

    // dynamic region, time-multiplexed (as R2)
    char* dyn = base + off;
    u16* img_bf    = (u16*)dyn;
    float* xall    = (float*)(dyn + (((size_t)kB*kN*kC*2 + 255) & ~(size_t)255));
    u16* logits_bf = (u16*)dyn;
    size_t poff = 0;
    auto palloc = [&](size_t bytes)->char*{
        char* p = dyn + poff;
        poff += ((bytes + 255) & ~(size_t)255);
        return p;
    };
    float* H_all   = (float*)palloc((size_t)kT*kB*kD*4);
    float* s_all   = (float*)palloc((size_t)kT*kB*kD*4);
    u16*   H_bfb   = (u16*)  palloc((size_t)kT*kB*kD*2);
    u16*   s_bfb   = (u16*)  palloc((size_t)kT*kB*kD*2);
    float* gH_all  = (float*)palloc((size_t)kT*kB*kN*4);
    float* sWs_all = (float*)palloc((size_t)kT*kB*kN*4);
    u16*   Hc_bf   = (u16*)  palloc((size_t)kT*kB*kD*2);

    auto G = [&](const u16* A, int lda, const u16* W, int ldw,
                 float* C, u16* Cbf, int ldc, int M, int N, int K,
                 const float* bias, const float* a1, int l1, int a1mask, int act){
        dim3 g((N + TBN - 1)/TBN, (M + TBM - 1)/TBM);
        gemm_bf16<<<g, 256, 0, stream>>>(A, lda, W, ldw, C, Cbf, ldc, M, N, K,
                                         bias, a1, l1, a1mask, act);
    };

    // ---- prep (4 launches) ----
    bias_prep_k<<<16, 256, 0, stream>>>(bih, bhh, bb, bhi, bmi, bias2560, bcat3, bctr);
    emb_gather_k<<<kT*kB*kE/256, 256, 0, stream>>>(target, emb, we_bf);
    img_cvt_mean_k<<<kB*kC/8/256, 256, 0, stream>>>(img, img_bf, meanb_bf);
    {
        CvtTab tab{};
        int idx = 0, start = 0;
        auto addCV = [&](const float* src, u16* dst, int src_ld, int Kshift, int rows){
            tab.d[idx] = {src, (unsigned long long)(size_t)dst, src_ld, Kshift, 0, 0, 0, start};
            start += rows << Kshift; ++idx;
        };
        auto addIL = [&](const float* src, _Float16* dst, int rows, int n_off, int Ntot){
            tab.d[idx] = {src, (unsigned long long)(size_t)dst, 512, 6, 1, n_off, Ntot, start};
            start += rows << 6; ++idx;
        };
        addCV(Wa,        Wa_bf,                       2048, 8, 512);
        addCV(Wb,        Winit_bf,                    2048, 8, 512);
        addCV(Whi,       Winit_bf + (size_t)512*kC,   2048, 8, 512);
        addCV(Wmi,       Winit_bf + (size_t)1024*kC,  2048, 8, 512);
        addCV(Wv,        Wv_bf,                        512, 6, 49);
        addCV(Wp,        Wp_bf,                        512, 6, 10000);
        addCV(Wih,       Wfirst_bf,                   1024, 6, 2048);
        addCV(Wx,        Wfirst_bf + (size_t)2048*512,1024, 6, 512);
        addCV(Wih + 512, Wlast_bf,                    1024, 6, 2048);
        addCV(Wx  + 512, Wlast_bf + (size_t)2048*512, 1024, 6, 512);
        addCV(W_H,       WH_bf,                        512, 6, 512);
        addCV(Wc,        Wc_bf,                        512, 6, 512);
        addCV(Wg,        Wg_bf,                        512, 6, 49);
        addCV(Wsm,       Ws_bf,                        512, 6, 49);
        addCV(Wfc,       Wfc_bf,                       512, 6, 512);
        addIL(Whh,       Wrec_il, 2048, 0,    2560);
        addIL(Wh2,       Wrec_il, 512,  2048, 2560);
        tab.total = start;
        int blocks = (start + 255)/256; if (blocks > 2048) blocks = 2048;
        multi_cvt_k<<<blocks, 256, 0, stream>>>(tab);
    }

    // ---- precompute GEMMs ----
    G(meanb_bf, kC, Winit_bf, kC, initC, init_bf, 1536, kB, 1536, kC, bcat3, nullptr, 0, -1, 1);
    G(img_bf, kC, Wa_bf, kC, nullptr, Vf_bf, kD, kB*kN, kD, kC, ba, nullptr, 0, -1, 1);
    G(Vf_bf, kD, Wv_bf, kD, zbase, nullptr, kN, kB*kN, kN, kD, nullptr, nullptr, 0, -1, 0);
    G(init_bf, 1536, Wfirst_bf, 512, gbase, nullptr, 2560, kB, 2560, kD, bias2560, nullptr, 0, -1, 0);
    G(we_bf, kE, Wlast_bf, 512, xall, nullptr, 2560, kT*kB, 2560, kE, nullptr, gbase, 2560, 127, 0);

    // ---- sequential LSTM recurrence: 256 blocks + device barrier per t ----
    scan_k<<<256, 512, 0, stream>>>(initC, xall, Wrec_il, hbuf, bctr, h2_bf, gtv_bf);

    // ---- deferred batched phases over M = T*B = 2560 rows ----
    G(h2_bf, kD, WH_bf, kD, H_all, H_bfb, kD, kT*kB, kD, kD, nullptr, nullptr, 0, -1, 1);
    G(gtv_bf, kD, Wc_bf, kD, s_all, s_bfb, kD, kT*kB, kD, kD, bc, nullptr, 0, -1, 1);
    G(H_bfb, kD, Wg_bf, kD, gH_all, nullptr, kN, kT*kB, kN, kD, nullptr, nullptr, 0, -1, 0);
    G(s_bfb, kD, Ws_bf, kD, sWs_all, nullptr, kN, kT*kB, kN, kD, nullptr, nullptr, 0, -1, 0);
    attn_k<<<kT*kB, 256, 0, stream>>>(gH_all, sWs_all, H_all, s_all, Vf_bf, zbase, wh,
                                      Hc_bf, attn_out);
    G(Hc_bf, kD, Wfc_bf, kD, nullptr, outbf, kD, kT*kB, kD, kD, bfc, nullptr, 0, -1, 2);

    // ---- logits (bf16) + log-softmax -> fp32 out ----
    G(outbf, kD, Wp_bf, kD, nullptr, logits_bf, kV, kT*kB, kV, kD, bp, nullptr, 0, -1, 0);
    logsoftmax_k<<<kB*kT, 256, 0, stream>>>(logits_bf, out0);
}

// Round 5
// 1384.569 us; speedup vs baseline: 1.7478x; 1.7478x over previous
//
#include <hip/hip_runtime.h>
#include <hip/hip_bf16.h>

// Problem dims
static const int kB = 128, kN = 49, kC = 2048, kD = 512, kE = 512, kV = 10000, kT = 20;

typedef __bf16 bf16x8 __attribute__((ext_vector_type(8)));
typedef float  f32x4v __attribute__((ext_vector_type(4)));
typedef _Float16 h8_t __attribute__((ext_vector_type(8)));
typedef _Float16 h2v_t __attribute__((ext_vector_type(2)));
typedef unsigned short u16;
typedef unsigned int u32;

#if defined(__has_builtin)
#if __has_builtin(__builtin_amdgcn_fdot2)
#define HAS_FDOT2 1
#endif
#endif
#ifndef HAS_FDOT2
#define HAS_FDOT2 0
#endif

#define AS1 __attribute__((address_space(1)))
#define AS3 __attribute__((address_space(3)))

__device__ __forceinline__ float sigmoidf_(float x){ return 1.f/(1.f+expf(-x)); }
__device__ __forceinline__ u16 f2b(float x){ __hip_bfloat16 h = __float2bfloat16(x); return *(u16*)&h; }
__device__ __forceinline__ float bu2f(u32 u){ u32 w = u << 16; union{u32 u; float f;} c; c.u = w; return c.f; }

// ================= bf16 MFMA NT GEMM =================
// C[M,N] = act(A[M,K]@W[N,K]^T + bias + add1[m&a1mask]) [*mul2 for act3], fp32 acc.
// REQUIRES: M % 128 == 0; W has >= ceil(N/128)*128 readable rows (padded
// workspace); staging uses global_load_lds width-16 (no bounds checks).
#define TBM 128
#define TBN 128
#define TBK 32

__global__ __launch_bounds__(256) void gemm_bf16(
    const u16* __restrict__ A, int lda,
    const u16* __restrict__ W, int ldw,
    float* __restrict__ C, u16* __restrict__ Cbf, int ldc,
    int M, int N, int K,
    const float* __restrict__ bias,
    const float* __restrict__ add1, int ld1, int a1mask,
    int act,
    const u16* __restrict__ mul2, int ldm)
{
    __shared__ __align__(16) u16 As[TBM*TBK];
    __shared__ __align__(16) u16 Bs[TBN*TBK];
    const int tid = threadIdx.x;
    const int bm = blockIdx.y * TBM;
    const int bn = blockIdx.x * TBN;
    const int wave = tid >> 6, lane = tid & 63;
    const int wm = (wave >> 1) * 64, wn = (wave & 1) * 64;
    const int lm = lane & 15, quad = lane >> 4;
    f32x4v acc[4][4] = {};
    for (int k0 = 0; k0 < K; k0 += TBK) {
        #pragma unroll
        for (int h = 0; h < 2; ++h) {
            const int slot = h*256 + tid;           // 0..511
            const int row = slot >> 2, kf = (slot & 3)*8;
            const int wbase = (h*256 + (tid & 448))*8;  // wave-uniform, u16 units
            __builtin_amdgcn_global_load_lds((const AS1 u32*)(A + (size_t)(bm + row)*lda + k0 + kf),
                                             (AS3 u32*)(As + wbase), 16, 0, 0);
            __builtin_amdgcn_global_load_lds((const AS1 u32*)(W + (size_t)(bn + row)*ldw + k0 + kf),
                                             (AS3 u32*)(Bs + wbase), 16, 0, 0);
        }
        __syncthreads();
        bf16x8 afr[4], bfr[4];
        #pragma unroll
        for (int i = 0; i < 4; ++i) afr[i] = *(const bf16x8*)&As[(wm + i*16 + lm)*TBK + quad*8];
        #pragma unroll
        for (int j = 0; j < 4; ++j) bfr[j] = *(const bf16x8*)&Bs[(wn + j*16 + lm)*TBK + quad*8];
        #pragma unroll
        for (int i = 0; i < 4; ++i)
            #pragma unroll
            for (int j = 0; j < 4; ++j)
                acc[i][j] = __builtin_amdgcn_mfma_f32_16x16x32_bf16(afr[i], bfr[j], acc[i][j], 0, 0, 0);
        __syncthreads();
    }
    #pragma unroll
    for (int i = 0; i < 4; ++i) {
        int mbase = bm + wm + i*16 + quad*4;
        #pragma unroll
        for (int j = 0; j < 4; ++j) {
            int n = bn + wn + j*16 + lm;
            if (n >= N) continue;
            float bv = bias ? bias[n] : 0.f;
            #pragma unroll
            for (int rr2 = 0; rr2 < 4; ++rr2) {
                int m = mbase + rr2;
                float v = acc[i][j][rr2] + bv;
                if (add1) v += add1[(size_t)(m & a1mask)*ld1 + n];
                if (act == 1) v = fmaxf(v, 0.f);
                else if (act == 2) v = tanhf(v);
                else if (act == 3) v = sigmoidf_(v) * bu2f(mul2[(size_t)m*ldm + n]);
                if (C)   C[(size_t)m*ldc + n] = v;
                if (Cbf) Cbf[(size_t)m*ldc + n] = f2b(v);
            }
        }
    }
}

// ================= fused conversion kernels =================
// img fp32 [B][49][2048] -> bf16 (same layout) AND mean over n -> bf16 [B][2048]
__global__ __launch_bounds__(256) void img_cvt_mean_k(const float* __restrict__ img,
                                                      u16* __restrict__ img_bf,
                                                      u16* __restrict__ meanb){
    int idx = blockIdx.x*256 + threadIdx.x;       // B * C/8 = 32768
    int b = idx >> 8, c8 = idx & 255;
    const float* p = img + (size_t)b*kN*kC + c8*8;
    f32x4v s0 = {0,0,0,0}, s1 = {0,0,0,0};
    for (int n = 0; n < kN; ++n){
        f32x4v f0 = *(const f32x4v*)(p + (size_t)n*kC);
        f32x4v f1 = *(const f32x4v*)(p + (size_t)n*kC + 4);
        s0 += f0; s1 += f1;
        union { u16 u[8]; uint4 v; } pk;
        pk.u[0]=f2b(f0[0]); pk.u[1]=f2b(f0[1]); pk.u[2]=f2b(f0[2]); pk.u[3]=f2b(f0[3]);
        pk.u[4]=f2b(f1[0]); pk.u[5]=f2b(f1[1]); pk.u[6]=f2b(f1[2]); pk.u[7]=f2b(f1[3]);
        *(uint4*)(img_bf + ((size_t)(b*kN + n))*kC + c8*8) = pk.v;
    }
    const float inv = 1.f/(float)kN;
    union { u16 u[8]; uint4 v; } pm;
    pm.u[0]=f2b(s0[0]*inv); pm.u[1]=f2b(s0[1]*inv); pm.u[2]=f2b(s0[2]*inv); pm.u[3]=f2b(s0[3]*inv);
    pm.u[4]=f2b(s1[0]*inv); pm.u[5]=f2b(s1[1]*inv); pm.u[6]=f2b(s1[2]*inv); pm.u[7]=f2b(s1[3]*inv);
    *(uint4*)(meanb + (size_t)b*kC + c8*8) = pm.v;
}

// all weight conversions in ONE kernel via descriptor table.
// mode bit0: f16 output (else bf16). mode bit1: permute rows dst = (rr&511)*4 + (rr>>9).
struct CvtDesc {
    const float* src;
    unsigned long long dst;
    int src_ld, Kshift, mode, start;
};
struct CvtTab { CvtDesc d[17]; int total; };

__global__ __launch_bounds__(256) void multi_cvt_k(CvtTab tab){
    for (int idx = blockIdx.x*256 + threadIdx.x; idx < tab.total; idx += gridDim.x*256){
        int di = 0;
        #pragma unroll
        for (int i = 1; i < 17; ++i) if (idx >= tab.d[i].start) di = i;
        const CvtDesc D = tab.d[di];
        int rel = idx - D.start;
        int rr = rel >> D.Kshift, kc = rel - (rr << D.Kshift);
        const float* p = D.src + (size_t)rr*D.src_ld + kc*8;
        f32x4v f0 = *(const f32x4v*)p, f1 = *(const f32x4v*)(p+4);
        int dr = (D.mode & 2) ? ((rr & 511)*4 + (rr >> 9)) : rr;
        size_t off = (((size_t)dr << D.Kshift) + kc)*8;
        if (D.mode & 1){
            h8_t o;
            o[0]=(_Float16)f0[0]; o[1]=(_Float16)f0[1]; o[2]=(_Float16)f0[2]; o[3]=(_Float16)f0[3];
            o[4]=(_Float16)f1[0]; o[5]=(_Float16)f1[1]; o[6]=(_Float16)f1[2]; o[7]=(_Float16)f1[3];
            *(h8_t*)((_Float16*)D.dst + off) = o;
        } else {
            union { u16 u[8]; uint4 v; } pk;
            pk.u[0]=f2b(f0[0]); pk.u[1]=f2b(f0[1]); pk.u[2]=f2b(f0[2]); pk.u[3]=f2b(f0[3]);
            pk.u[4]=f2b(f1[0]); pk.u[5]=f2b(f1[1]); pk.u[6]=f2b(f1[2]); pk.u[7]=f2b(f1[3]);
            *(uint4*)((u16*)D.dst + off) = pk.v;
        }
    }
}

// bias2560 = [perm4(bih+bhh) (2048); 0 (512)]; bcat3 = [bb|bhi|bmi]
__global__ __launch_bounds__(256) void bias_prep_k(const float* bih, const float* bhh,
                                                   const float* bb, const float* bhi, const float* bmi,
                                                   float* bias2560, float* bcat3){
    int i = blockIdx.x*256 + threadIdx.x;
    if (i < 2048) bias2560[(i & 511)*4 + (i >> 9)] = bih[i] + bhh[i];
    else if (i < 2560) bias2560[i] = 0.f;
    else if (i < 4096){
        int j = i - 2560;
        bcat3[j] = (j < 512) ? bb[j] : (j < 1024 ? bhi[j-512] : bmi[j-1024]);
    }
}

// we[t*B+b][e] bf16
__global__ __launch_bounds__(256) void emb_gather_k(const int* __restrict__ target,
                                                    const float* __restrict__ emb,
                                                    u16* __restrict__ we){
    int idx = blockIdx.x*256 + threadIdx.x;       // T*B*E
    int e = idx & (kE-1);
    int rr = idx >> 9;                            // t*B + b
    int b = rr & 127, t = rr >> 7;
    float v = 0.f;
    if (t > 0){ int tok = target[b*kT + (t-1)]; v = emb[(size_t)tok*kE + e]; }
    we[idx] = f2b(v);
}

// hp row0 (h0) + mstate init from initC
__global__ __launch_bounds__(256) void initcopy_k(const float* __restrict__ initC,
                                                  _Float16* __restrict__ hp_f16,
                                                  u16* __restrict__ hp_bf,
                                                  float* __restrict__ mstate){
    int idx = blockIdx.x*256 + threadIdx.x;       // 128*512
    int b = idx >> 9, d = idx & 511;
    float h0 = initC[(size_t)b*1536 + 512 + d];
    float m0 = initC[(size_t)b*1536 + 1024 + d];
    hp_f16[idx] = (_Float16)h0;
    hp_bf[idx]  = f2b(h0);
    mstate[idx] = m0;
}

// ================= per-timestep LSTM gates: weights-stationary, batch-parallel =================
// One launch per timestep (stream order = sync). 256 blocks = 64 row-slices x 4 batch-quarters.
// Gate weights reordered to quadruple layout: row 4d+g. gtv's Wh2 part deferred to a GEMM.
__device__ __forceinline__ float dot8f(h8_t a, h8_t b, float c){
#if HAS_FDOT2
    const h2v_t* ap = (const h2v_t*)&a;
    const h2v_t* bp = (const h2v_t*)&b;
    c = __builtin_amdgcn_fdot2(ap[0], bp[0], c, false);
    c = __builtin_amdgcn_fdot2(ap[1], bp[1], c, false);
    c = __builtin_amdgcn_fdot2(ap[2], bp[2], c, false);
    c = __builtin_amdgcn_fdot2(ap[3], bp[3], c, false);
#else
    #pragma unroll
    for (int i = 0; i < 8; ++i) c = fmaf((float)a[i], (float)b[i], c);
#endif
    return c;
}

__global__ __launch_bounds__(256) void step_k(
    const _Float16* __restrict__ hp,   // [128][512] f16 = hp_f16 + t*65536
    const float* __restrict__ xrow,    // xall + t*128*2560 (cols 0..2047 quadruple-ordered)
    const _Float16* __restrict__ Wg4,  // [2048][512] f16, row 4d+g
    float* __restrict__ mstate,        // [128][512] fp32 (persistent)
    _Float16* __restrict__ hn_f16,     // hp_f16 + (t+1)*65536
    u16* __restrict__ hn_bf,           // hp_bf + (t+1)*65536
    u16* __restrict__ tmrow)           // tm_bf + t*65536
{
    const int jr = blockIdx.x & 63, jb = blockIdx.x >> 6;
    const int tid = threadIdx.x;
    const int rq = tid & 7, bq = tid >> 3;   // rq: output-in-slice [0,8), bq: batch [0,32)
    __shared__ __align__(16) _Float16 sH[32*520];   // 33 KB, padded rows
    for (int c = tid; c < 32*64; c += 256){
        int rl = c >> 6, k8 = c & 63;
        *(h8_t*)&sH[rl*520 + k8*8] = *(const h8_t*)&hp[(size_t)(32*jb + rl)*512 + k8*8];
    }
    __syncthreads();
    const int d = 8*jr + rq;
    const int b = 32*jb + bq;
    const _Float16* w0 = Wg4 + (size_t)(4*d)*512;   // rows 4d..4d+3 contiguous
    const _Float16* hr = &sH[bq*520];
    float a0=0.f, a1=0.f, a2=0.f, a3=0.f;
    #pragma unroll 4
    for (int k8 = 0; k8 < 64; ++k8){
        h8_t hv  = *(const h8_t*)&hr[k8*8];
        h8_t wv0 = *(const h8_t*)&w0[k8*8];
        h8_t wv1 = *(const h8_t*)&w0[512 + k8*8];
        h8_t wv2 = *(const h8_t*)&w0[1024 + k8*8];
        h8_t wv3 = *(const h8_t*)&w0[1536 + k8*8];
        a0 = dot8f(hv, wv0, a0);
        a1 = dot8f(hv, wv1, a1);
        a2 = dot8f(hv, wv2, a2);
        a3 = dot8f(hv, wv3, a3);
    }
    f32x4v xv = *(const f32x4v*)(xrow + (size_t)b*2560 + 4*d);
    a0 += xv[0]; a1 += xv[1]; a2 += xv[2]; a3 += xv[3];
    float i_g = sigmoidf_(a0), f_g = sigmoidf_(a1);
    float g_g = tanhf(a2),     o_g = sigmoidf_(a3);
    size_t md = (size_t)b*512 + d;
    float m2 = f_g*mstate[md] + i_g*g_g;
    mstate[md] = m2;
    float tm = tanhf(m2);
    float h2 = o_g*tm;
    hn_f16[md] = (_Float16)h2;
    hn_bf[md]  = f2b(h2);
    tmrow[md]  = f2b(tm);
}

// ================= batched attention kernel: one block per (t,b) row =================
__global__ __launch_bounds__(256) void attn_k(
    const float* __restrict__ gH_all,      // [2560][49]
    const float* __restrict__ sWs_all,     // [2560][49]
    const float* __restrict__ H_all,       // [2560][512] fp32
    const float* __restrict__ s_all,       // [2560][512] fp32
    const u16* __restrict__ Vf_bf,         // [128*49][512] bf16
    const float* __restrict__ zbase,       // [128][49][49]
    const float* __restrict__ wh,          // [49]
    u16* __restrict__ Hc_bf,               // [2560][512] bf16
    float* __restrict__ attn_out)          // [128][20][49] fp32
{
    const int r = blockIdx.x, tid = threadIdx.x;   // r = t*128 + b
    const int b = r & 127, t = r >> 7;
    __shared__ float sgH[52], ssWs[52], swh[52], sz[52], salpha[52];

    if (tid < 49){
        sgH[tid]  = gH_all [(size_t)r*49 + tid];
        ssWs[tid] = sWs_all[(size_t)r*49 + tid];
        swh[tid]  = wh[tid];
    }
    __syncthreads();
    if (tid < 49){
        const float* zb = zbase + (size_t)b*2401 + (size_t)tid*49;
        float a = 0.f;
        #pragma unroll
        for (int k = 0; k < 49; ++k) a += tanhf(zb[k] + sgH[k]) * swh[k];
        sz[tid] = a;
    }
    if (tid == 64){
        float a = 0.f;
        #pragma unroll
        for (int k = 0; k < 49; ++k) a += tanhf(ssWs[k] + sgH[k]) * swh[k];
        sz[49] = a;
    }
    __syncthreads();
    if (tid < 64){
        float val = (tid < 50) ? sz[tid] : -1e30f;
        float mx = val;
        #pragma unroll
        for (int o = 32; o > 0; o >>= 1) mx = fmaxf(mx, __shfl_xor(mx, o));
        float e = (tid < 50) ? __expf(val - mx) : 0.f;
        float ssum = e;
        #pragma unroll
        for (int o = 32; o > 0; o >>= 1) ssum += __shfl_xor(ssum, o);
        float a = e/ssum;
        if (tid < 50) salpha[tid] = a;
        if (tid < 49) attn_out[((size_t)b*kT + t)*kN + tid] = a;
    }
    __syncthreads();
    for (int d = tid; d < 512; d += 256){
        float a = salpha[49] * s_all[(size_t)r*512 + d];
        const u16* vf = Vf_bf + (size_t)b*49*512 + d;
        #pragma unroll
        for (int n = 0; n < 49; ++n) a = fmaf(salpha[n], bu2f(vf[(size_t)n*512]), a);
        Hc_bf[(size_t)r*512 + d] = f2b(H_all[(size_t)r*512 + d] + a);
    }
}

// ================= log-softmax: read bf16 logits row (t*128+b), write fp32 row (b*20+t) =================
__global__ __launch_bounds__(256) void logsoftmax_k(const u16* __restrict__ logits_bf,
                                                    float* __restrict__ out0)
{
    const int r = blockIdx.x, tid = threadIdx.x;   // r = b*20+t
    const int b = r / 20, t = r - b*20;
    const u16* L = logits_bf + (size_t)(t*kB + b)*kV;
    __shared__ float rm[256], rs[256];
    float m = -1e30f, s = 0.f;
    for (int c = tid; c < kV/8; c += 256){
        uint4 v = *(const uint4*)(L + c*8);
        u32 w[4] = {v.x, v.y, v.z, v.w};
        #pragma unroll
        for (int j = 0; j < 4; ++j){
            float x0 = bu2f(w[j] & 0xffff), x1 = bu2f(w[j] >> 16);
            float nm = fmaxf(m, fmaxf(x0, x1));
            s = s*__expf(m - nm) + __expf(x0 - nm) + __expf(x1 - nm);
            m = nm;
        }
    }
    rm[tid] = m; rs[tid] = s; __syncthreads();
    for (int st = 128; st > 0; st >>= 1){
        if (tid < st){
            float m2 = rm[tid + st], s2 = rs[tid + st];
            float nm = fmaxf(rm[tid], m2);
            rs[tid] = rs[tid]*__expf(rm[tid] - nm) + s2*__expf(m2 - nm);
            rm[tid] = nm;
        }
        __syncthreads();
    }
    float lse = rm[0] + logf(rs[0]);
    float* D = out0 + (size_t)r*kV;
    for (int c = tid; c < kV/8; c += 256){
        uint4 v = *(const uint4*)(L + c*8);
        u32 w[4] = {v.x, v.y, v.z, v.w};
        f32x4v o0, o1;
        o0[0]=bu2f(w[0]&0xffff)-lse; o0[1]=bu2f(w[0]>>16)-lse;
        o0[2]=bu2f(w[1]&0xffff)-lse; o0[3]=bu2f(w[1]>>16)-lse;
        o1[0]=bu2f(w[2]&0xffff)-lse; o1[1]=bu2f(w[2]>>16)-lse;
        o1[2]=bu2f(w[3]&0xffff)-lse; o1[3]=bu2f(w[3]>>16)-lse;
        *(f32x4v*)(D + c*8) = o0;
        *(f32x4v*)(D + c*8 + 4) = o1;
    }
}

extern "C" void kernel_launch(void* const* d_in, const int* in_sizes, int n_in,
                              void* d_out, int out_size, void* d_ws, size_t ws_size,
                              hipStream_t stream)
{
    const float* img   = (const float*)d_in[0];
    const int*   target= (const int*)  d_in[1];
    const float* emb   = (const float*)d_in[2];
    const float* Wa    = (const float*)d_in[3];
    const float* ba    = (const float*)d_in[4];
    const float* Wb    = (const float*)d_in[5];
    const float* bb    = (const float*)d_in[6];
    const float* Whi   = (const float*)d_in[7];
    const float* bhi   = (const float*)d_in[8];
    const float* Wmi   = (const float*)d_in[9];
    const float* bmi   = (const float*)d_in[10];
    const float* Wih   = (const float*)d_in[11];
    const float* bih   = (const float*)d_in[12];
    const float* Whh   = (const float*)d_in[13];
    const float* bhh   = (const float*)d_in[14];
    const float* Wv    = (const float*)d_in[15];
    const float* Wg    = (const float*)d_in[16];
    const float* wh    = (const float*)d_in[17];
    const float* W_H   = (const float*)d_in[18];
    const float* Wx    = (const float*)d_in[19];
    const float* Wh2   = (const float*)d_in[20];
    const float* Wsm   = (const float*)d_in[21];
    const float* Wc    = (const float*)d_in[22];
    const float* bc    = (const float*)d_in[23];
    const float* Wfc   = (const float*)d_in[24];
    const float* bfc   = (const float*)d_in[25];
    const float* Wp    = (const float*)d_in[26];
    const float* bp    = (const float*)d_in[27];
    (void)in_sizes; (void)n_in; (void)out_size; (void)ws_size;

    float* out0 = (float*)d_out;                       // [B*T, V] logprobs (row b*20+t)
    float* attn_out = out0 + (size_t)kB*kT*kV;         // [B, T, N]

    char* base = (char*)d_ws;
    size_t off = 0;
    auto alloc = [&](size_t bytes)->char*{
        char* p = base + off;
        off += ((bytes + 255) & ~(size_t)255);
        return p;
    };
    // fixed region (W arrays padded to 128-row multiples for unchecked staging)
    u16* Wa_bf     = (u16*)alloc((size_t)kD*kC*2);
    u16* Winit_bf  = (u16*)alloc((size_t)1536*kC*2);
    u16* Wv_bf     = (u16*)alloc((size_t)128*kD*2);           // 49 -> 128 rows
    u16* Wp_bf     = (u16*)alloc((size_t)10112*kD*2);         // 10000 -> 10112 rows
    u16* Wfirst_bf = (u16*)alloc((size_t)2560*512*2); // [perm4(Wih[:, :512]); Wx[:, :512]]
    u16* Wlast_bf  = (u16*)alloc((size_t)2560*512*2); // [perm4(Wih[:, 512:]); Wx[:, 512:]]
    _Float16* Wg4  = (_Float16*)alloc((size_t)2048*512*2);    // perm4(Whh), f16
    u16* Wh2_bf    = (u16*)alloc((size_t)512*512*2);
    u16* WH_bf     = (u16*)alloc((size_t)512*512*2);
    u16* Wc_bf     = (u16*)alloc((size_t)512*512*2);
    u16* Wg_bf     = (u16*)alloc((size_t)128*512*2);          // 49 -> 128 rows
    u16* Ws_bf     = (u16*)alloc((size_t)128*512*2);          // 49 -> 128 rows
    u16* Wfc_bf    = (u16*)alloc((size_t)512*512*2);
    float* bias2560 = (float*)alloc(2560*4);
    float* bcat3    = (float*)alloc(1536*4);
    u16* meanb_bf   = (u16*)alloc((size_t)kB*kC*2);
    float* initC    = (float*)alloc((size_t)kB*1536*4);
    u16* init_bf    = (u16*)alloc((size_t)kB*1536*2);
    u16* Vf_bf      = (u16*)alloc((size_t)kB*kN*kD*2);
    float* zbase    = (float*)alloc((size_t)kB*kN*kN*4);
    u16* we_bf      = (u16*)alloc((size_t)kT*kB*kE*2);
    float* gbase    = (float*)alloc((size_t)kB*2560*4);
    u16* outbf      = (u16*)alloc((size_t)kT*kB*kD*2);
    u16* gtv_bf     = (u16*)alloc((size_t)kT*kB*kD*2);
    _Float16* hp_f16 = (_Float16*)alloc((size_t)(kT+1)*kB*kD*2); // h sequence f16 (recurrence)
    u16* hp_bf      = (u16*)alloc((size_t)(kT+1)*kB*kD*2);       // h sequence bf16 (GEMM input)
    u16* tm_bf      = (u16*)alloc((size_t)kT*kB*kD*2);           // tanh(m2) per step
    float* mstate   = (float*)alloc((size_t)kB*kD*4);

    // dynamic region, time-multiplexed
    char* dyn = base + off;
    u16* img_bf    = (u16*)dyn;
    float* xall    = (float*)(dyn + (((size_t)kB*kN*kC*2 + 255) & ~(size_t)255));
    u16* logits_bf = (u16*)dyn;
    size_t poff = 0;
    auto palloc = [&](size_t bytes)->char*{
        char* p = dyn + poff;
        poff += ((bytes + 255) & ~(size_t)255);
        return p;
    };
    float* H_all   = (float*)palloc((size_t)kT*kB*kD*4);
    float* s_all   = (float*)palloc((size_t)kT*kB*kD*4);
    u16*   H_bfb   = (u16*)  palloc((size_t)kT*kB*kD*2);
    u16*   s_bfb   = (u16*)  palloc((size_t)kT*kB*kD*2);
    float* gH_all  = (float*)palloc((size_t)kT*kB*kN*4);
    float* sWs_all = (float*)palloc((size_t)kT*kB*kN*4);
    u16*   Hc_bf   = (u16*)  palloc((size_t)kT*kB*kD*2);
    // phase-2 buffers ~19.4MB < img_bf's 25.7MB: xall intact until gtv GEMM.

    auto G = [&](const u16* A, int lda, const u16* W, int ldw,
                 float* C, u16* Cbf, int ldc, int M, int N, int K,
                 const float* bias, const float* a1, int l1, int a1mask, int act,
                 const u16* mul2 = nullptr, int ldm = 0){
        dim3 g((N + TBN - 1)/TBN, (M + TBM - 1)/TBM);
        gemm_bf16<<<g, 256, 0, stream>>>(A, lda, W, ldw, C, Cbf, ldc, M, N, K,
                                         bias, a1, l1, a1mask, act, mul2, ldm);
    };

    // ---- prep (4 launches) ----
    bias_prep_k<<<16, 256, 0, stream>>>(bih, bhh, bb, bhi, bmi, bias2560, bcat3);
    emb_gather_k<<<kT*kB*kE/256, 256, 0, stream>>>(target, emb, we_bf);
    img_cvt_mean_k<<<kB*kC/8/256, 256, 0, stream>>>(img, img_bf, meanb_bf);
    {
        CvtTab tab{};
        int idx = 0, start = 0;
        auto add = [&](const float* src, void* dst, int src_ld, int Kshift, int rows, int mode){
            tab.d[idx] = {src, (unsigned long long)(size_t)dst, src_ld, Kshift, mode, start};
            start += rows << Kshift; ++idx;
        };
        add(Wa,        Wa_bf,                        2048, 8, 512,   0);
        add(Wb,        Winit_bf,                     2048, 8, 512,   0);
        add(Whi,       Winit_bf + (size_t)512*kC,    2048, 8, 512,   0);
        add(Wmi,       Winit_bf + (size_t)1024*kC,   2048, 8, 512,   0);
        add(Wv,        Wv_bf,                         512, 6, 49,    0);
        add(Wp,        Wp_bf,                         512, 6, 10000, 0);
        add(Wih,       Wfirst_bf,                    1024, 6, 2048,  2);  // perm4
        add(Wx,        Wfirst_bf + (size_t)2048*512, 1024, 6, 512,   0);
        add(Wih + 512, Wlast_bf,                     1024, 6, 2048,  2);  // perm4
        add(Wx  + 512, Wlast_bf + (size_t)2048*512,  1024, 6, 512,   0);
        add(W_H,       WH_bf,                         512, 6, 512,   0);
        add(Wc,        Wc_bf,                         512, 6, 512,   0);
        add(Wg,        Wg_bf,                         512, 6, 49,    0);
        add(Wsm,       Ws_bf,                         512, 6, 49,    0);
        add(Wfc,       Wfc_bf,                        512, 6, 512,   0);
        add(Whh,       Wg4,                           512, 6, 2048,  3);  // perm4 + f16
        add(Wh2,       Wh2_bf,                        512, 6, 512,   0);
        tab.total = start;
        int blocks = (start + 255)/256; if (blocks > 2048) blocks = 2048;
        multi_cvt_k<<<blocks, 256, 0, stream>>>(tab);
    }

    // ---- precompute GEMMs ----
    // [vg|h0|m0] = relu(mean @ [Wb;Whi;Wmi]^T + bcat3)
    G(meanb_bf, kC, Winit_bf, kC, initC, init_bf, 1536, kB, 1536, kC, bcat3, nullptr, 0, -1, 1);
    initcopy_k<<<kB*kD/256, 256, 0, stream>>>(initC, hp_f16, hp_bf, mstate);
    // Vf = relu(img @ Wa^T + ba)
    G(img_bf, kC, Wa_bf, kC, nullptr, Vf_bf, kD, kB*kN, kD, kC, ba, nullptr, 0, -1, 1);
    // zbase = Vf @ Wv^T
    G(Vf_bf, kD, Wv_bf, kD, zbase, nullptr, kN, kB*kN, kN, kD, nullptr, nullptr, 0, -1, 0);
    // gbase[b] = vg @ [perm4(Wih);Wx][:, :512]^T + bias2560 (quadruple-ordered cols 0..2047)
    G(init_bf, 1536, Wfirst_bf, 512, gbase, nullptr, 2560, kB, 2560, kD, bias2560, nullptr, 0, -1, 0);
    // xall[t*128+b] = we @ [perm4(Wih);Wx][:, 512:]^T + gbase[b]
    G(we_bf, kE, Wlast_bf, 512, xall, nullptr, 2560, kT*kB, 2560, kE, nullptr, gbase, 2560, 127, 0);

    // ---- sequential LSTM recurrence: 20 launches, weights-stationary ----
    for (int t = 0; t < kT; ++t){
        step_k<<<256, 256, 0, stream>>>(hp_f16 + (size_t)t*kB*kD,
                                        xall + (size_t)t*kB*2560,
                                        Wg4, mstate,
                                        hp_f16 + (size_t)(t+1)*kB*kD,
                                        hp_bf + (size_t)(t+1)*kB*kD,
                                        tm_bf + (size_t)t*kB*kD);
    }

    // ---- deferred batched phases over M = T*B = 2560 rows ----
    // gtv = sigmoid(xall[:,2048:2560] + hprev @ Wh2^T) * tanh(m2)   (bf16)
    G(hp_bf, kD, Wh2_bf, kD, nullptr, gtv_bf, kD, kT*kB, kD, kD,
      nullptr, xall + 2048, 2560, 0x7fffffff, 3, tm_bf, kD);
    // H = relu(h2 @ WH^T)
    G(hp_bf + (size_t)kB*kD, kD, WH_bf, kD, H_all, H_bfb, kD, kT*kB, kD, kD, nullptr, nullptr, 0, -1, 1);
    // s = relu(gtv @ Wc^T + bc)
    G(gtv_bf, kD, Wc_bf, kD, s_all, s_bfb, kD, kT*kB, kD, kD, bc, nullptr, 0, -1, 1);
    // gH = H @ Wg^T
    G(H_bfb, kD, Wg_bf, kD, gH_all, nullptr, kN, kT*kB, kN, kD, nullptr, nullptr, 0, -1, 0);
    // sWs = s @ Ws^T
    G(s_bfb, kD, Ws_bf, kD, sWs_all, nullptr, kN, kT*kB, kN, kD, nullptr, nullptr, 0, -1, 0);
    attn_k<<<kT*kB, 256, 0, stream>>>(gH_all, sWs_all, H_all, s_all, Vf_bf, zbase, wh,
                                      Hc_bf, attn_out);
    // out = tanh(Hc @ Wfc^T + bfc)
    G(Hc_bf, kD, Wfc_bf, kD, nullptr, outbf, kD, kT*kB, kD, kD, bfc, nullptr, 0, -1, 2);

    // ---- logits (bf16) + log-softmax -> fp32 out ----
    G(outbf, kD, Wp_bf, kD, nullptr, logits_bf, kV, kT*kB, kV, kD, bp, nullptr, 0, -1, 0);
    logsoftmax_k<<<kB*kT, 256, 0, stream>>>(logits_bf, out0);
}

// Round 6
// 1039.003 us; speedup vs baseline: 2.3291x; 1.3326x over previous
//
#include <hip/hip_runtime.h>
#include <hip/hip_bf16.h>

// Problem dims
static const int kB = 128, kN = 49, kC = 2048, kD = 512, kE = 512, kV = 10000, kT = 20;

typedef __bf16 bf16x8 __attribute__((ext_vector_type(8)));
typedef float  f32x4v __attribute__((ext_vector_type(4)));
typedef _Float16 h8_t __attribute__((ext_vector_type(8)));
typedef _Float16 h2v_t __attribute__((ext_vector_type(2)));
typedef unsigned short u16;
typedef unsigned int u32;

#if defined(__has_builtin)
#if __has_builtin(__builtin_amdgcn_fdot2)
#define HAS_FDOT2 1
#endif
#endif
#ifndef HAS_FDOT2
#define HAS_FDOT2 0
#endif

#define AS1 __attribute__((address_space(1)))
#define AS3 __attribute__((address_space(3)))

__device__ __forceinline__ float sigmoidf_(float x){ return 1.f/(1.f+expf(-x)); }
__device__ __forceinline__ u16 f2b(float x){ __hip_bfloat16 h = __float2bfloat16(x); return *(u16*)&h; }
__device__ __forceinline__ float bu2f(u32 u){ u32 w = u << 16; union{u32 u; float f;} c; c.u = w; return c.f; }

// ================= bf16 MFMA NT GEMM =================
// C[M,N] = act(A[M,K]@W[N,K]^T + bias + add1[m&a1mask]) [*mul2 for act3], fp32 acc.
// REQUIRES: M % 128 == 0; W has >= ceil(N/128)*128 readable rows (padded
// workspace); staging uses global_load_lds width-16 (no bounds checks).
// swz!=0: 1D grid, XCD-grouped decode (XCD k owns N-tiles == k mod 8, M-major
// within) so each XCD's W working set stays L2-resident.
#define TBM 128
#define TBN 128
#define TBK 32

__global__ __launch_bounds__(256) void gemm_bf16(
    const u16* __restrict__ A, int lda,
    const u16* __restrict__ W, int ldw,
    float* __restrict__ C, u16* __restrict__ Cbf, int ldc,
    int M, int N, int K,
    const float* __restrict__ bias,
    const float* __restrict__ add1, int ld1, int a1mask,
    int act,
    const u16* __restrict__ mul2, int ldm,
    int swz)
{
    __shared__ __align__(16) u16 As[TBM*TBK];
    __shared__ __align__(16) u16 Bs[TBN*TBK];
    const int tid = threadIdx.x;
    int bm, bn;
    if (swz){
        const int mblocks = (M + TBM - 1)/TBM;
        const int per_g = mblocks*8;
        const int id = blockIdx.x;
        const int g = id/per_g, r = id - g*per_g;
        bm = (r >> 3)*TBM;
        bn = (g*8 + (r & 7))*TBN;
        if (bn >= N) return;               // uniform per block, before any barrier
    } else {
        bm = blockIdx.y * TBM;
        bn = blockIdx.x * TBN;
    }
    const int wave = tid >> 6, lane = tid & 63;
    const int wm = (wave >> 1) * 64, wn = (wave & 1) * 64;
    const int lm = lane & 15, quad = lane >> 4;
    f32x4v acc[4][4] = {};
    for (int k0 = 0; k0 < K; k0 += TBK) {
        #pragma unroll
        for (int h = 0; h < 2; ++h) {
            const int slot = h*256 + tid;           // 0..511
            const int row = slot >> 2, kf = (slot & 3)*8;
            const int wbase = (h*256 + (tid & 448))*8;  // wave-uniform, u16 units
            __builtin_amdgcn_global_load_lds((const AS1 u32*)(A + (size_t)(bm + row)*lda + k0 + kf),
                                             (AS3 u32*)(As + wbase), 16, 0, 0);
            __builtin_amdgcn_global_load_lds((const AS1 u32*)(W + (size_t)(bn + row)*ldw + k0 + kf),
                                             (AS3 u32*)(Bs + wbase), 16, 0, 0);
        }
        __syncthreads();
        bf16x8 afr[4], bfr[4];
        #pragma unroll
        for (int i = 0; i < 4; ++i) afr[i] = *(const bf16x8*)&As[(wm + i*16 + lm)*TBK + quad*8];
        #pragma unroll
        for (int j = 0; j < 4; ++j) bfr[j] = *(const bf16x8*)&Bs[(wn + j*16 + lm)*TBK + quad*8];
        #pragma unroll
        for (int i = 0; i < 4; ++i)
            #pragma unroll
            for (int j = 0; j < 4; ++j)
                acc[i][j] = __builtin_amdgcn_mfma_f32_16x16x32_bf16(afr[i], bfr[j], acc[i][j], 0, 0, 0);
        __syncthreads();
    }
    #pragma unroll
    for (int i = 0; i < 4; ++i) {
        int mbase = bm + wm + i*16 + quad*4;
        #pragma unroll
        for (int j = 0; j < 4; ++j) {
            int n = bn + wn + j*16 + lm;
            if (n >= N) continue;
            float bv = bias ? bias[n] : 0.f;
            #pragma unroll
            for (int rr2 = 0; rr2 < 4; ++rr2) {
                int m = mbase + rr2;
                float v = acc[i][j][rr2] + bv;
                if (add1) v += add1[(size_t)(m & a1mask)*ld1 + n];
                if (act == 1) v = fmaxf(v, 0.f);
                else if (act == 2) v = tanhf(v);
                else if (act == 3) v = sigmoidf_(v) * bu2f(mul2[(size_t)m*ldm + n]);
                if (C)   C[(size_t)m*ldc + n] = v;
                if (Cbf) Cbf[(size_t)m*ldc + n] = f2b(v);
            }
        }
    }
}

// ================= fused conversion kernels =================
// img fp32 [B][49][2048] -> bf16 (same layout) AND mean over n -> bf16 [B][2048]
__global__ __launch_bounds__(256) void img_cvt_mean_k(const float* __restrict__ img,
                                                      u16* __restrict__ img_bf,
                                                      u16* __restrict__ meanb){
    int idx = blockIdx.x*256 + threadIdx.x;       // B * C/8 = 32768
    int b = idx >> 8, c8 = idx & 255;
    const float* p = img + (size_t)b*kN*kC + c8*8;
    f32x4v s0 = {0,0,0,0}, s1 = {0,0,0,0};
    for (int n = 0; n < kN; ++n){
        f32x4v f0 = *(const f32x4v*)(p + (size_t)n*kC);
        f32x4v f1 = *(const f32x4v*)(p + (size_t)n*kC + 4);
        s0 += f0; s1 += f1;
        union { u16 u[8]; uint4 v; } pk;
        pk.u[0]=f2b(f0[0]); pk.u[1]=f2b(f0[1]); pk.u[2]=f2b(f0[2]); pk.u[3]=f2b(f0[3]);
        pk.u[4]=f2b(f1[0]); pk.u[5]=f2b(f1[1]); pk.u[6]=f2b(f1[2]); pk.u[7]=f2b(f1[3]);
        *(uint4*)(img_bf + ((size_t)(b*kN + n))*kC + c8*8) = pk.v;
    }
    const float inv = 1.f/(float)kN;
    union { u16 u[8]; uint4 v; } pm;
    pm.u[0]=f2b(s0[0]*inv); pm.u[1]=f2b(s0[1]*inv); pm.u[2]=f2b(s0[2]*inv); pm.u[3]=f2b(s0[3]*inv);
    pm.u[4]=f2b(s1[0]*inv); pm.u[5]=f2b(s1[1]*inv); pm.u[6]=f2b(s1[2]*inv); pm.u[7]=f2b(s1[3]*inv);
    *(uint4*)(meanb + (size_t)b*kC + c8*8) = pm.v;
}

// all weight conversions in ONE kernel via descriptor table.
// mode 0: fp32[rows][src_ld] -> bf16 [rows][K] linear
// mode 5: fp32[rows=2048][src_ld] -> f16 interleaved [64][2048][8] (Wrec4)
struct CvtDesc {
    const float* src;
    unsigned long long dst;
    int src_ld, Kshift, mode, start;
};
struct CvtTab { CvtDesc d[17]; int total; };

__global__ __launch_bounds__(256) void multi_cvt_k(CvtTab tab){
    for (int idx = blockIdx.x*256 + threadIdx.x; idx < tab.total; idx += gridDim.x*256){
        int di = 0;
        #pragma unroll
        for (int i = 1; i < 17; ++i) if (idx >= tab.d[i].start) di = i;
        const CvtDesc D = tab.d[di];
        int rel = idx - D.start;
        int rr = rel >> D.Kshift, kc = rel - (rr << D.Kshift);
        const float* p = D.src + (size_t)rr*D.src_ld + kc*8;
        f32x4v f0 = *(const f32x4v*)p, f1 = *(const f32x4v*)(p+4);
        if (D.mode == 0){
            union { u16 u[8]; uint4 v; } pk;
            pk.u[0]=f2b(f0[0]); pk.u[1]=f2b(f0[1]); pk.u[2]=f2b(f0[2]); pk.u[3]=f2b(f0[3]);
            pk.u[4]=f2b(f1[0]); pk.u[5]=f2b(f1[1]); pk.u[6]=f2b(f1[2]); pk.u[7]=f2b(f1[3]);
            *(uint4*)((u16*)D.dst + (((size_t)rr << D.Kshift) + kc)*8) = pk.v;
        } else {
            // f16 interleaved: dst[(kc*2048 + rr)*8 + e]
            h8_t o;
            o[0]=(_Float16)f0[0]; o[1]=(_Float16)f0[1]; o[2]=(_Float16)f0[2]; o[3]=(_Float16)f0[3];
            o[4]=(_Float16)f1[0]; o[5]=(_Float16)f1[1]; o[6]=(_Float16)f1[2]; o[7]=(_Float16)f1[3];
            *(h8_t*)((_Float16*)D.dst + ((size_t)kc*2048 + rr)*8) = o;
        }
    }
}

// bias2560 = [bih+bhh (2048); 0 (512)]; bcat3 = [bb|bhi|bmi]
__global__ __launch_bounds__(256) void bias_prep_k(const float* bih, const float* bhh,
                                                   const float* bb, const float* bhi, const float* bmi,
                                                   float* bias2560, float* bcat3){
    int i = blockIdx.x*256 + threadIdx.x;
    if (i < 2048) bias2560[i] = bih[i] + bhh[i];
    else if (i < 2560) bias2560[i] = 0.f;
    else if (i < 4096){
        int j = i - 2560;
        bcat3[j] = (j < 512) ? bb[j] : (j < 1024 ? bhi[j-512] : bmi[j-1024]);
    }
}

// we[t*B+b][e] bf16
__global__ __launch_bounds__(256) void emb_gather_k(const int* __restrict__ target,
                                                    const float* __restrict__ emb,
                                                    u16* __restrict__ we){
    int idx = blockIdx.x*256 + threadIdx.x;       // T*B*E
    int e = idx & (kE-1);
    int rr = idx >> 9;                            // t*B + b
    int b = rr & 127, t = rr >> 7;
    float v = 0.f;
    if (t > 0){ int tok = target[b*kT + (t-1)]; v = emb[(size_t)tok*kE + e]; }
    we[idx] = f2b(v);
}

// hp_bf row block 0 = h0 (bf16) for the gtv GEMM
__global__ __launch_bounds__(256) void initcopy_k(const float* __restrict__ initC,
                                                  u16* __restrict__ hp_bf){
    int idx = blockIdx.x*256 + threadIdx.x;       // 128*512
    int b = idx >> 9, d = idx & 511;
    hp_bf[idx] = f2b(initC[(size_t)b*1536 + 512 + d]);
}

// ================= single-launch LSTM recurrence (R2 structure, 4 gates) =================
// 128 blocks x 1024 threads: thread = (out in [0,512), kh in {0,1} K-half).
// Weight stream 2.1 MB/step/CU from L2; gtv's 5th gate group deferred to a GEMM.
__device__ __forceinline__ float dot8f(h8_t a, h8_t b, float c){
#if HAS_FDOT2
    const h2v_t* ap = (const h2v_t*)&a;
    const h2v_t* bp = (const h2v_t*)&b;
    c = __builtin_amdgcn_fdot2(ap[0], bp[0], c, false);
    c = __builtin_amdgcn_fdot2(ap[1], bp[1], c, false);
    c = __builtin_amdgcn_fdot2(ap[2], bp[2], c, false);
    c = __builtin_amdgcn_fdot2(ap[3], bp[3], c, false);
#else
    #pragma unroll
    for (int i = 0; i < 8; ++i) c = fmaf((float)a[i], (float)b[i], c);
#endif
    return c;
}

__global__ __launch_bounds__(1024, 1) void scan_k(
    const float* __restrict__ initC,       // [128][1536] vg|h0|m0 (fp32)
    const float* __restrict__ xall,        // [20][128][2560] gate-major cols 0..2047
    const _Float16* __restrict__ Wrec,     // il [64][2048][8] (Whh, 4 gates)
    u16* __restrict__ hp_bf,               // [21*128][512]: row (t+1)*128+b written here
    u16* __restrict__ tm_bf)               // [20*128][512]: tanh(m2)
{
    const int b = blockIdx.x, tid = threadIdx.x;
    const int out = tid & 511, kh = tid >> 9;
    __shared__ __align__(16) _Float16 sh[512];
    __shared__ float spart[512][4];

    if (tid < 512) sh[tid] = (_Float16)initC[(size_t)b*1536 + 512 + tid];
    float m_reg = (kh == 0) ? initC[(size_t)b*1536 + 1024 + out] : 0.f;
    __syncthreads();

    for (int t = 0; t < kT; ++t){
        float a0=0.f, a1=0.f, a2=0.f, a3=0.f;
        const int kc0 = kh*32;
        #pragma unroll 2
        for (int kc = kc0; kc < kc0 + 32; ++kc){
            h8_t hv = *(const h8_t*)&sh[kc*8];
            const _Float16* wb = Wrec + (size_t)kc*2048*8;
            a0 = dot8f(hv, *(const h8_t*)&wb[(size_t)(out       )*8], a0);
            a1 = dot8f(hv, *(const h8_t*)&wb[(size_t)(out +  512)*8], a1);
            a2 = dot8f(hv, *(const h8_t*)&wb[(size_t)(out + 1024)*8], a2);
            a3 = dot8f(hv, *(const h8_t*)&wb[(size_t)(out + 1536)*8], a3);
        }
        __syncthreads();                      // all GEMV reads of sh done
        if (kh == 1){
            spart[out][0]=a0; spart[out][1]=a1; spart[out][2]=a2; spart[out][3]=a3;
        }
        __syncthreads();
        if (kh == 0){
            const float* xrow = xall + ((size_t)t*kB + b)*2560;
            a0 += spart[out][0] + xrow[out];
            a1 += spart[out][1] + xrow[out + 512];
            a2 += spart[out][2] + xrow[out + 1024];
            a3 += spart[out][3] + xrow[out + 1536];
            float i_g = sigmoidf_(a0), f_g = sigmoidf_(a1);
            float g_g = tanhf(a2),     o_g = sigmoidf_(a3);
            m_reg = f_g*m_reg + i_g*g_g;
            float tm = tanhf(m_reg);
            float h2 = o_g*tm;
            sh[out] = (_Float16)h2;
            hp_bf[((size_t)(t+1)*kB + b)*512 + out] = f2b(h2);
            tm_bf[((size_t)t*kB + b)*512 + out] = f2b(tm);
        }
        __syncthreads();
    }
}

// ================= batched attention kernel (fused gH/sWs GEMVs): one block per (t,b) =================
__global__ __launch_bounds__(256) void attn_k(
    const float* __restrict__ H_all,       // [2560][512] fp32
    const float* __restrict__ s_all,       // [2560][512] fp32
    const u16* __restrict__ Wg_bf,         // [128pad][512] bf16
    const u16* __restrict__ Ws_bf,         // [128pad][512] bf16
    const u16* __restrict__ Vf_bf,         // [128*49][512] bf16
    const float* __restrict__ zbase,       // [128][49][49]
    const float* __restrict__ wh,          // [49]
    u16* __restrict__ Hc_bf,               // [2560][512] bf16
    float* __restrict__ attn_out)          // [128][20][49] fp32
{
    const int r = blockIdx.x, tid = threadIdx.x;   // r = t*128 + b
    const int b = r & 127, t = r >> 7;
    __shared__ float sH2[512], ss2[512];
    __shared__ float sgH[52], ssWs[52], swh[52], sz[52], salpha[52];

    for (int d = tid; d < 512; d += 256){
        sH2[d] = H_all[(size_t)r*512 + d];
        ss2[d] = s_all[(size_t)r*512 + d];
    }
    if (tid < 49) swh[tid] = wh[tid];
    __syncthreads();
    // gH[n] = H . Wg[n]  (lanes 0-48);  sWs[n] = s . Ws[n]  (lanes 64-112)
    if (tid < 49){
        const u16* wr = Wg_bf + (size_t)tid*512;
        float a = 0.f;
        for (int k = 0; k < 512; k += 8){
            uint4 v = *(const uint4*)(wr + k);
            a += bu2f(v.x&0xffff)*sH2[k]   + bu2f(v.x>>16)*sH2[k+1]
               + bu2f(v.y&0xffff)*sH2[k+2] + bu2f(v.y>>16)*sH2[k+3]
               + bu2f(v.z&0xffff)*sH2[k+4] + bu2f(v.z>>16)*sH2[k+5]
               + bu2f(v.w&0xffff)*sH2[k+6] + bu2f(v.w>>16)*sH2[k+7];
        }
        sgH[tid] = a;
    } else if (tid >= 64 && tid < 113){
        int n = tid - 64;
        const u16* wr = Ws_bf + (size_t)n*512;
        float a = 0.f;
        for (int k = 0; k < 512; k += 8){
            uint4 v = *(const uint4*)(wr + k);
            a += bu2f(v.x&0xffff)*ss2[k]   + bu2f(v.x>>16)*ss2[k+1]
               + bu2f(v.y&0xffff)*ss2[k+2] + bu2f(v.y>>16)*ss2[k+3]
               + bu2f(v.z&0xffff)*ss2[k+4] + bu2f(v.z>>16)*ss2[k+5]
               + bu2f(v.w&0xffff)*ss2[k+6] + bu2f(v.w>>16)*ss2[k+7];
        }
        ssWs[n] = a;
    }
    __syncthreads();
    if (tid < 49){
        const float* zb = zbase + (size_t)b*2401 + (size_t)tid*49;
        float a = 0.f;
        #pragma unroll
        for (int k = 0; k < 49; ++k) a += tanhf(zb[k] + sgH[k]) * swh[k];
        sz[tid] = a;
    } else if (tid == 64){
        float a = 0.f;
        #pragma unroll
        for (int k = 0; k < 49; ++k) a += tanhf(ssWs[k] + sgH[k]) * swh[k];
        sz[49] = a;
    }
    __syncthreads();
    if (tid < 64){
        float val = (tid < 50) ? sz[tid] : -1e30f;
        float mx = val;
        #pragma unroll
        for (int o = 32; o > 0; o >>= 1) mx = fmaxf(mx, __shfl_xor(mx, o));
        float e = (tid < 50) ? __expf(val - mx) : 0.f;
        float ssum = e;
        #pragma unroll
        for (int o = 32; o > 0; o >>= 1) ssum += __shfl_xor(ssum, o);
        float a = e/ssum;
        if (tid < 50) salpha[tid] = a;
        if (tid < 49) attn_out[((size_t)b*kT + t)*kN + tid] = a;
    }
    __syncthreads();
    for (int d = tid; d < 512; d += 256){
        float a = salpha[49] * ss2[d];
        const u16* vf = Vf_bf + (size_t)b*49*512 + d;
        #pragma unroll
        for (int n = 0; n < 49; ++n) a = fmaf(salpha[n], bu2f(vf[(size_t)n*512]), a);
        Hc_bf[(size_t)r*512 + d] = f2b(sH2[d] + a);
    }
}

// ================= log-softmax: read bf16 logits row (t*128+b), write fp32 row (b*20+t) =================
__global__ __launch_bounds__(256) void logsoftmax_k(const u16* __restrict__ logits_bf,
                                                    float* __restrict__ out0)
{
    const int r = blockIdx.x, tid = threadIdx.x;   // r = b*20+t
    const int b = r / 20, t = r - b*20;
    const u16* L = logits_bf + (size_t)(t*kB + b)*kV;
    __shared__ float rm[256], rs[256];
    float m = -1e30f, s = 0.f;
    for (int c = tid; c < kV/8; c += 256){
        uint4 v = *(const uint4*)(L + c*8);
        u32 w[4] = {v.x, v.y, v.z, v.w};
        #pragma unroll
        for (int j = 0; j < 4; ++j){
            float x0 = bu2f(w[j] & 0xffff), x1 = bu2f(w[j] >> 16);
            float nm = fmaxf(m, fmaxf(x0, x1));
            s = s*__expf(m - nm) + __expf(x0 - nm) + __expf(x1 - nm);
            m = nm;
        }
    }
    rm[tid] = m; rs[tid] = s; __syncthreads();
    for (int st = 128; st > 0; st >>= 1){
        if (tid < st){
            float m2 = rm[tid + st], s2 = rs[tid + st];
            float nm = fmaxf(rm[tid], m2);
            rs[tid] = rs[tid]*__expf(rm[tid] - nm) + s2*__expf(m2 - nm);
            rm[tid] = nm;
        }
        __syncthreads();
    }
    float lse = rm[0] + logf(rs[0]);
    float* D = out0 + (size_t)r*kV;
    for (int c = tid; c < kV/8; c += 256){
        uint4 v = *(const uint4*)(L + c*8);
        u32 w[4] = {v.x, v.y, v.z, v.w};
        f32x4v o0, o1;
        o0[0]=bu2f(w[0]&0xffff)-lse; o0[1]=bu2f(w[0]>>16)-lse;
        o0[2]=bu2f(w[1]&0xffff)-lse; o0[3]=bu2f(w[1]>>16)-lse;
        o1[0]=bu2f(w[2]&0xffff)-lse; o1[1]=bu2f(w[2]>>16)-lse;
        o1[2]=bu2f(w[3]&0xffff)-lse; o1[3]=bu2f(w[3]>>16)-lse;
        *(f32x4v*)(D + c*8) = o0;
        *(f32x4v*)(D + c*8 + 4) = o1;
    }
}

extern "C" void kernel_launch(void* const* d_in, const int* in_sizes, int n_in,
                              void* d_out, int out_size, void* d_ws, size_t ws_size,
                              hipStream_t stream)
{
    const float* img   = (const float*)d_in[0];
    const int*   target= (const int*)  d_in[1];
    const float* emb   = (const float*)d_in[2];
    const float* Wa    = (const float*)d_in[3];
    const float* ba    = (const float*)d_in[4];
    const float* Wb    = (const float*)d_in[5];
    const float* bb    = (const float*)d_in[6];
    const float* Whi   = (const float*)d_in[7];
    const float* bhi   = (const float*)d_in[8];
    const float* Wmi   = (const float*)d_in[9];
    const float* bmi   = (const float*)d_in[10];
    const float* Wih   = (const float*)d_in[11];
    const float* bih   = (const float*)d_in[12];
    const float* Whh   = (const float*)d_in[13];
    const float* bhh   = (const float*)d_in[14];
    const float* Wv    = (const float*)d_in[15];
    const float* Wg    = (const float*)d_in[16];
    const float* wh    = (const float*)d_in[17];
    const float* W_H   = (const float*)d_in[18];
    const float* Wx    = (const float*)d_in[19];
    const float* Wh2   = (const float*)d_in[20];
    const float* Wsm   = (const float*)d_in[21];
    const float* Wc    = (const float*)d_in[22];
    const float* bc    = (const float*)d_in[23];
    const float* Wfc   = (const float*)d_in[24];
    const float* bfc   = (const float*)d_in[25];
    const float* Wp    = (const float*)d_in[26];
    const float* bp    = (const float*)d_in[27];
    (void)in_sizes; (void)n_in; (void)out_size; (void)ws_size;

    float* out0 = (float*)d_out;                       // [B*T, V] logprobs (row b*20+t)
    float* attn_out = out0 + (size_t)kB*kT*kV;         // [B, T, N]

    char* base = (char*)d_ws;
    size_t off = 0;
    auto alloc = [&](size_t bytes)->char*{
        char* p = base + off;
        off += ((bytes + 255) & ~(size_t)255);
        return p;
    };
    // fixed region (W arrays padded to 128-row multiples for unchecked staging)
    u16* Wa_bf     = (u16*)alloc((size_t)kD*kC*2);
    u16* Winit_bf  = (u16*)alloc((size_t)1536*kC*2);
    u16* Wv_bf     = (u16*)alloc((size_t)128*kD*2);           // 49 -> 128 rows
    u16* Wp_bf     = (u16*)alloc((size_t)10112*kD*2);         // 10000 -> 10112 rows
    u16* Wfirst_bf = (u16*)alloc((size_t)2560*512*2); // [Wih[:, :512]; Wx[:, :512]]
    u16* Wlast_bf  = (u16*)alloc((size_t)2560*512*2); // [Wih[:, 512:]; Wx[:, 512:]]
    _Float16* Wrec4 = (_Float16*)alloc((size_t)2048*512*2);   // il [64][2048][8] (Whh)
    u16* Wh2_bf    = (u16*)alloc((size_t)512*512*2);
    u16* WH_bf     = (u16*)alloc((size_t)512*512*2);
    u16* Wc_bf     = (u16*)alloc((size_t)512*512*2);
    u16* Wg_bf     = (u16*)alloc((size_t)128*512*2);          // 49 -> 128 rows
    u16* Ws_bf     = (u16*)alloc((size_t)128*512*2);          // 49 -> 128 rows
    u16* Wfc_bf    = (u16*)alloc((size_t)512*512*2);
    float* bias2560 = (float*)alloc(2560*4);
    float* bcat3    = (float*)alloc(1536*4);
    u16* meanb_bf   = (u16*)alloc((size_t)kB*kC*2);
    float* initC    = (float*)alloc((size_t)kB*1536*4);
    u16* init_bf    = (u16*)alloc((size_t)kB*1536*2);
    u16* Vf_bf      = (u16*)alloc((size_t)kB*kN*kD*2);
    float* zbase    = (float*)alloc((size_t)kB*kN*kN*4);
    u16* we_bf      = (u16*)alloc((size_t)kT*kB*kE*2);
    float* gbase    = (float*)alloc((size_t)kB*2560*4);
    u16* outbf      = (u16*)alloc((size_t)kT*kB*kD*2);
    u16* gtv_bf     = (u16*)alloc((size_t)kT*kB*kD*2);
    u16* hp_bf      = (u16*)alloc((size_t)(kT+1)*kB*kD*2);    // h sequence bf16 (h0..h20)
    u16* tm_bf      = (u16*)alloc((size_t)kT*kB*kD*2);        // tanh(m2) per step

    // dynamic region, time-multiplexed
    char* dyn = base + off;
    u16* img_bf    = (u16*)dyn;
    float* xall    = (float*)(dyn + (((size_t)kB*kN*kC*2 + 255) & ~(size_t)255));
    u16* logits_bf = (u16*)dyn;
    size_t poff = 0;
    auto palloc = [&](size_t bytes)->char*{
        char* p = dyn + poff;
        poff += ((bytes + 255) & ~(size_t)255);
        return p;
    };
    float* H_all   = (float*)palloc((size_t)kT*kB*kD*4);
    float* s_all   = (float*)palloc((size_t)kT*kB*kD*4);
    u16*   Hc_bf   = (u16*)  palloc((size_t)kT*kB*kD*2);
    // phase-2 buffers ~13MB < img_bf's 25.7MB: xall intact until gtv GEMM.

    auto G = [&](const u16* A, int lda, const u16* W, int ldw,
                 float* C, u16* Cbf, int ldc, int M, int N, int K,
                 const float* bias, const float* a1, int l1, int a1mask, int act,
                 const u16* mul2 = nullptr, int ldm = 0){
        dim3 g((N + TBN - 1)/TBN, (M + TBM - 1)/TBM);
        gemm_bf16<<<g, 256, 0, stream>>>(A, lda, W, ldw, C, Cbf, ldc, M, N, K,
                                         bias, a1, l1, a1mask, act, mul2, ldm, 0);
    };

    // ---- prep (4 launches) ----
    bias_prep_k<<<16, 256, 0, stream>>>(bih, bhh, bb, bhi, bmi, bias2560, bcat3);
    emb_gather_k<<<kT*kB*kE/256, 256, 0, stream>>>(target, emb, we_bf);
    img_cvt_mean_k<<<kB*kC/8/256, 256, 0, stream>>>(img, img_bf, meanb_bf);
    {
        CvtTab tab{};
        int idx = 0, start = 0;
        auto add = [&](const float* src, void* dst, int src_ld, int Kshift, int rows, int mode){
            tab.d[idx] = {src, (unsigned long long)(size_t)dst, src_ld, Kshift, mode, start};
            start += rows << Kshift; ++idx;
        };
        add(Wa,        Wa_bf,                        2048, 8, 512,   0);
        add(Wb,        Winit_bf,                     2048, 8, 512,   0);
        add(Whi,       Winit_bf + (size_t)512*kC,    2048, 8, 512,   0);
        add(Wmi,       Winit_bf + (size_t)1024*kC,   2048, 8, 512,   0);
        add(Wv,        Wv_bf,                         512, 6, 49,    0);
        add(Wp,        Wp_bf,                         512, 6, 10000, 0);
        add(Wih,       Wfirst_bf,                    1024, 6, 2048,  0);
        add(Wx,        Wfirst_bf + (size_t)2048*512, 1024, 6, 512,   0);
        add(Wih + 512, Wlast_bf,                     1024, 6, 2048,  0);
        add(Wx  + 512, Wlast_bf + (size_t)2048*512,  1024, 6, 512,   0);
        add(W_H,       WH_bf,                         512, 6, 512,   0);
        add(Wc,        Wc_bf,                         512, 6, 512,   0);
        add(Wg,        Wg_bf,                         512, 6, 49,    0);
        add(Wsm,       Ws_bf,                         512, 6, 49,    0);
        add(Wfc,       Wfc_bf,                        512, 6, 512,   0);
        add(Whh,       Wrec4,                         512, 6, 2048,  5);  // f16 interleaved
        add(Wh2,       Wh2_bf,                        512, 6, 512,   0);
        tab.total = start;
        int blocks = (start + 255)/256; if (blocks > 2048) blocks = 2048;
        multi_cvt_k<<<blocks, 256, 0, stream>>>(tab);
    }

    // ---- precompute GEMMs ----
    // [vg|h0|m0] = relu(mean @ [Wb;Whi;Wmi]^T + bcat3)
    G(meanb_bf, kC, Winit_bf, kC, initC, init_bf, 1536, kB, 1536, kC, bcat3, nullptr, 0, -1, 1);
    initcopy_k<<<kB*kD/256, 256, 0, stream>>>(initC, hp_bf);
    // Vf = relu(img @ Wa^T + ba)
    G(img_bf, kC, Wa_bf, kC, nullptr, Vf_bf, kD, kB*kN, kD, kC, ba, nullptr, 0, -1, 1);
    // zbase = Vf @ Wv^T
    G(Vf_bf, kD, Wv_bf, kD, zbase, nullptr, kN, kB*kN, kN, kD, nullptr, nullptr, 0, -1, 0);
    // gbase[b] = vg @ [Wih;Wx][:, :512]^T + [bih+bhh; 0]
    G(init_bf, 1536, Wfirst_bf, 512, gbase, nullptr, 2560, kB, 2560, kD, bias2560, nullptr, 0, -1, 0);
    // xall[t*128+b] = we @ [Wih;Wx][:, 512:]^T + gbase[b]
    G(we_bf, kE, Wlast_bf, 512, xall, nullptr, 2560, kT*kB, 2560, kE, nullptr, gbase, 2560, 127, 0);

    // ---- sequential LSTM recurrence: ONE launch (4-gate, gtv deferred) ----
    scan_k<<<kB, 1024, 0, stream>>>(initC, xall, Wrec4, hp_bf, tm_bf);

    // ---- deferred batched phases over M = T*B = 2560 rows ----
    // gtv = sigmoid(xall[:,2048:2560] + hprev @ Wh2^T) * tanh(m2)   (bf16)
    G(hp_bf, kD, Wh2_bf, kD, nullptr, gtv_bf, kD, kT*kB, kD, kD,
      nullptr, xall + 2048, 2560, 0x7fffffff, 3, tm_bf, kD);
    // H = relu(h2 @ WH^T)  (fp32 only)
    G(hp_bf + (size_t)kB*kD, kD, WH_bf, kD, H_all, nullptr, kD, kT*kB, kD, kD, nullptr, nullptr, 0, -1, 1);
    // s = relu(gtv @ Wc^T + bc)  (fp32 only)
    G(gtv_bf, kD, Wc_bf, kD, s_all, nullptr, kD, kT*kB, kD, kD, bc, nullptr, 0, -1, 1);
    // gH/sWs fused into attn_k (was two 20-block GEMM dispatches)
    attn_k<<<kT*kB, 256, 0, stream>>>(H_all, s_all, Wg_bf, Ws_bf, Vf_bf, zbase, wh,
                                      Hc_bf, attn_out);
    // out = tanh(Hc @ Wfc^T + bfc)
    G(Hc_bf, kD, Wfc_bf, kD, nullptr, outbf, kD, kT*kB, kD, kD, bfc, nullptr, 0, -1, 2);

    // ---- logits (bf16, XCD-grouped swizzle) + log-softmax -> fp32 out ----
    {
        const int mblocks = (kT*kB + TBM - 1)/TBM;          // 20
        const int nblocks = (kV + TBN - 1)/TBN;             // 79
        const int groups  = (nblocks + 7)/8;                // 10
        dim3 g(groups*8*mblocks, 1);                        // 1600
        gemm_bf16<<<g, 256, 0, stream>>>(outbf, kD, Wp_bf, kD, nullptr, logits_bf, kV,
                                         kT*kB, kV, kD, bp, nullptr, 0, -1, 0, nullptr, 0, 1);
    }
    logsoftmax_k<<<kB*kT, 256, 0, stream>>>(logits_bf, out0);
}